// Round 7
// baseline (152.743 us; speedup 1.0000x reference)
//
#include <hip/hip_runtime.h>

#define ROWS 1024
#define COLS 1024
#define NN (ROWS*COLS)

#define TILE_H 64
#define TILE_W 32
#define HALO   16              // steps fused per launch
#define RH     96              // TILE_H + 2*HALO
#define RW     64              // TILE_W + 2*HALO
#define RC     (RH*RW)         // 6144 cells
#define SPR    (RW/4)          // 16 float4-strips per region row
#define NSTRIP (RC/4)          // 1536
#define NT     384             // 6 waves; == number of 4x4 blocks
#define BR     (RH/4)          // 24 block-rows
#define BC     (RW/4)          // 16 block-cols

static constexpr float RHOG    = 1000.0f * 9.81f;
static constexpr float INV_SEC = 1.0f / 31556926.0f;
static constexpr float FLOWC   = 0.0405f;

__device__ __forceinline__ float4 gld4(const float* __restrict__ p, int g, bool in) {
    if (in) return *reinterpret_cast<const float4*>(p + g);
    return make_float4(0.f, 0.f, 0.f, 0.f);
}

// ---- prologue: phi, inv_total, runoff -------------------------------------
__global__ __launch_bounds__(256) void k_pre(
        const float* __restrict__ bed, const float* __restrict__ pw,
        const int* __restrict__ status,
        const float* __restrict__ melt, const float* __restrict__ area,
        float* __restrict__ phi, float* __restrict__ inv,
        float* __restrict__ runoff) {
    int i = blockIdx.x * 256 + threadIdx.x;
    int r = i >> 10, c = i & (COLS - 1);
    float p = RHOG * bed[i] + pw[i];
    float t = 0.f;
    if (c > 0)        t += fmaxf(p - (RHOG * bed[i - 1]    + pw[i - 1]),    0.f);
    if (c < COLS - 1) t += fmaxf(p - (RHOG * bed[i + 1]    + pw[i + 1]),    0.f);
    if (r > 0)        t += fmaxf(p - (RHOG * bed[i - COLS] + pw[i - COLS]), 0.f);
    if (r < ROWS - 1) t += fmaxf(p - (RHOG * bed[i + COLS] + pw[i + COLS]), 0.f);
    phi[i]    = p;
    inv[i]    = (status[i] == 0 && t > 0.f) ? (1.f / t) : 0.f;
    runoff[i] = melt[i] * area[i] * INV_SEC;
}

// ---- fused 16-step halo-tiled Jacobi, 4x4 cells/thread --------------------
// Region 96x64 around a 64x32 tile. Weights derived once from LDS-staged
// phi/inv into registers; step loop touches LDS only at 4x4-block edges via
// contiguous float4 planes (double-buffered). phi/inv staging and the planes
// occupy the SAME 48 KB of LDS (lifetimes disjoint). Border-distance freeze
// (q^min(s,d)) as in R6; interior blocks (depth>=16) never freeze.
template <bool FIRST, bool FINAL>
__global__ __launch_bounds__(NT) void k_fused(
        const float* __restrict__ phi_g, const float* __restrict__ inv_g,
        const float* __restrict__ run_g, const float* __restrict__ qin,
        float* __restrict__ qout,
        const float* __restrict__ cond, const int* __restrict__ status) {
    __shared__ __align__(16) char smem[8 * NT * 16];   // 49152 B, unioned
    float*  A   = (float*)smem;                        // phi staging [RC]
    float*  Bv  = A + RC;                              // inv staging [RC]
    float4* plT = (float4*)smem;                       // [2][NT] each
    float4* plB = plT + 2 * NT;
    float4* plL = plB + 2 * NT;
    float4* plR = plL + 2 * NT;

    const int tid = threadIdx.x;
    const int r0 = (int)blockIdx.y * TILE_H - HALO;
    const int c0 = (int)blockIdx.x * TILE_W - HALO;

    // phase 1: stage phi, inv (4 strips/thread)
#pragma unroll
    for (int k = 0; k < 4; ++k) {
        int sidx = tid + k * NT;
        int sr = sidx / SPR, sc4 = (sidx - sr * SPR) * 4;
        int gr = r0 + sr, gc = c0 + sc4;
        bool in = (gr >= 0) & (gr < ROWS) & (gc >= 0) & (gc < COLS);
        int g = gr * COLS + gc;
        *reinterpret_cast<float4*>(&A[sr * RW + sc4])  = gld4(phi_g, g, in);
        *reinterpret_cast<float4*>(&Bv[sr * RW + sc4]) = gld4(inv_g, g, in);
    }
    __syncthreads();

    const int br = tid / BC, bc = tid - (tid / BC) * BC;
    const int rr0 = 4 * br, cc0 = 4 * bc;
    const bool inter = (br >= HALO / 4) & (br < BR - HALO / 4) &
                       (bc >= HALO / 4) & (bc < BC - HALO / 4);

    float wW[4][4], wE[4][4], wN[4][4], wS[4][4];
    float q[4][4], ro[4][4];
    int dd[4][4];

    // phase 2: weights from LDS phi/inv into registers
#pragma unroll
    for (int i = 0; i < 4; ++i) {
        int rr = rr0 + i;
        int x = rr * RW + cc0;
        float4 pc = *reinterpret_cast<const float4*>(&A[x]);
        float4 ic = *reinterpret_cast<const float4*>(&Bv[x]);
        int xu = (rr > 0)      ? x - RW : x;
        int xd = (rr < RH - 1) ? x + RW : x;
        float4 pu = *reinterpret_cast<const float4*>(&A[xu]);
        float4 iu = *reinterpret_cast<const float4*>(&Bv[xu]);
        float4 pd = *reinterpret_cast<const float4*>(&A[xd]);
        float4 id = *reinterpret_cast<const float4*>(&Bv[xd]);
        float pl = (cc0 > 0)      ? A[x - 1]  : pc.x;
        float il = (cc0 > 0)      ? Bv[x - 1] : 0.f;
        float pr = (cc0 < RW - 4) ? A[x + 4]  : pc.w;
        float ir = (cc0 < RW - 4) ? Bv[x + 4] : 0.f;
        wN[i][0] = fmaxf(pu.x - pc.x, 0.f) * iu.x;
        wN[i][1] = fmaxf(pu.y - pc.y, 0.f) * iu.y;
        wN[i][2] = fmaxf(pu.z - pc.z, 0.f) * iu.z;
        wN[i][3] = fmaxf(pu.w - pc.w, 0.f) * iu.w;
        wS[i][0] = fmaxf(pd.x - pc.x, 0.f) * id.x;
        wS[i][1] = fmaxf(pd.y - pc.y, 0.f) * id.y;
        wS[i][2] = fmaxf(pd.z - pc.z, 0.f) * id.z;
        wS[i][3] = fmaxf(pd.w - pc.w, 0.f) * id.w;
        wW[i][0] = fmaxf(pl   - pc.x, 0.f) * il;
        wW[i][1] = fmaxf(pc.x - pc.y, 0.f) * ic.x;
        wW[i][2] = fmaxf(pc.y - pc.z, 0.f) * ic.y;
        wW[i][3] = fmaxf(pc.z - pc.w, 0.f) * ic.z;
        wE[i][0] = fmaxf(pc.y - pc.x, 0.f) * ic.y;
        wE[i][1] = fmaxf(pc.z - pc.y, 0.f) * ic.z;
        wE[i][2] = fmaxf(pc.w - pc.z, 0.f) * ic.w;
        wE[i][3] = fmaxf(pr   - pc.w, 0.f) * ir;
    }
#pragma unroll
    for (int i = 0; i < 4; ++i)
#pragma unroll
        for (int j = 0; j < 4; ++j) {
            int rr = rr0 + i, cc = cc0 + j;
            dd[i][j] = min(min(rr, RH - 1 - rr), min(cc, RW - 1 - cc));
        }
    // runoff + q0 straight from global to registers
#pragma unroll
    for (int i = 0; i < 4; ++i) {
        int gr = r0 + rr0 + i, gc = c0 + cc0;
        bool in = (gr >= 0) & (gr < ROWS) & (gc >= 0) & (gc < COLS);
        int g = gr * COLS + gc;
        float4 r4 = gld4(run_g, g, in);
        ro[i][0] = r4.x; ro[i][1] = r4.y; ro[i][2] = r4.z; ro[i][3] = r4.w;
        float4 q4 = FIRST ? r4 : gld4(qin, g, in);
        q[i][0] = q4.x; q[i][1] = q4.y; q[i][2] = q4.z; q[i][3] = q4.w;
    }
    __syncthreads();   // all phi/inv reads done — safe to overwrite with planes

    plT[tid]      = make_float4(q[0][0], q[0][1], q[0][2], q[0][3]);
    plB[tid]      = make_float4(q[3][0], q[3][1], q[3][2], q[3][3]);
    plL[tid]      = make_float4(q[0][0], q[1][0], q[2][0], q[3][0]);
    plR[tid]      = make_float4(q[0][3], q[1][3], q[2][3], q[3][3]);
    __syncthreads();

    // phase 3: 16 Jacobi steps; LDS only at block edges
    for (int s = 0; s < HALO; ++s) {
        const int pp = s & 1, pn = pp ^ 1;
        float4 up = plB[pp * NT + ((br > 0)      ? tid - BC : tid)];
        float4 dn = plT[pp * NT + ((br < BR - 1) ? tid + BC : tid)];
        float4 lf = plR[pp * NT + ((bc > 0)      ? tid - 1  : tid)];
        float4 rt = plL[pp * NT + ((bc < BC - 1) ? tid + 1  : tid)];
        float upv[4] = {up.x, up.y, up.z, up.w};
        float dnv[4] = {dn.x, dn.y, dn.z, dn.w};
        float lfv[4] = {lf.x, lf.y, lf.z, lf.w};
        float rtv[4] = {rt.x, rt.y, rt.z, rt.w};
        float nq[4][4];
#pragma unroll
        for (int i = 0; i < 4; ++i)
#pragma unroll
            for (int j = 0; j < 4; ++j) {
                float uv = (i > 0) ? q[i - 1][j] : upv[j];
                float dv = (i < 3) ? q[i + 1][j] : dnv[j];
                float lv = (j > 0) ? q[i][j - 1] : lfv[i];
                float rv = (j < 3) ? q[i][j + 1] : rtv[i];
                float a = ro[i][j];
                a = fmaf(wW[i][j], lv, a);
                a = fmaf(wE[i][j], rv, a);
                a = fmaf(wN[i][j], uv, a);
                a = fmaf(wS[i][j], dv, a);
                nq[i][j] = a;
            }
        if (!inter) {          // border blocks freeze cells past their depth
#pragma unroll
            for (int i = 0; i < 4; ++i)
#pragma unroll
                for (int j = 0; j < 4; ++j)
                    nq[i][j] = (s < dd[i][j]) ? nq[i][j] : q[i][j];
        }
#pragma unroll
        for (int i = 0; i < 4; ++i)
#pragma unroll
            for (int j = 0; j < 4; ++j) q[i][j] = nq[i][j];
        plT[pn * NT + tid] = make_float4(q[0][0], q[0][1], q[0][2], q[0][3]);
        plB[pn * NT + tid] = make_float4(q[3][0], q[3][1], q[3][2], q[3][3]);
        plL[pn * NT + tid] = make_float4(q[0][0], q[1][0], q[2][0], q[3][0]);
        plR[pn * NT + tid] = make_float4(q[0][3], q[1][3], q[2][3], q[3][3]);
        __syncthreads();
    }

    // phase 4: interior blocks == the 64x32 output tile exactly
    if (inter) {
#pragma unroll
        for (int i = 0; i < 4; ++i) {
            int g = (r0 + rr0 + i) * COLS + (c0 + cc0);
            if (FINAL) {
                float4 c4 = *reinterpret_cast<const float4*>(cond + g);
                int4 st   = *reinterpret_cast<const int4*>(status + g);
                float4 o;
                float t;
                t = q[i][0] * FLOWC * (c4.x * sqrtf(sqrtf(c4.x))); o.x = (st.x == 0) ? t * t : 0.f;
                t = q[i][1] * FLOWC * (c4.y * sqrtf(sqrtf(c4.y))); o.y = (st.y == 0) ? t * t : 0.f;
                t = q[i][2] * FLOWC * (c4.z * sqrtf(sqrtf(c4.z))); o.z = (st.z == 0) ? t * t : 0.f;
                t = q[i][3] * FLOWC * (c4.w * sqrtf(sqrtf(c4.w))); o.w = (st.w == 0) ? t * t : 0.f;
                *reinterpret_cast<float4*>(qout + g) = o;
            } else {
                *reinterpret_cast<float4*>(qout + g) =
                    make_float4(q[i][0], q[i][1], q[i][2], q[i][3]);
            }
        }
    }
}

extern "C" void kernel_launch(void* const* d_in, const int* in_sizes, int n_in,
                              void* d_out, int out_size, void* d_ws, size_t ws_size,
                              hipStream_t stream) {
    const float* melt   = (const float*)d_in[0];
    const float* bed    = (const float*)d_in[1];
    const float* pw     = (const float*)d_in[2];
    const float* area   = (const float*)d_in[3];
    const float* cond   = (const float*)d_in[4];
    const int*   status = (const int*)d_in[5];
    float* out = (float*)d_out;

    char* ws = (char*)d_ws;
    float* phi    = (float*)(ws);                 //  4 MB
    float* inv    = (float*)(ws + 4ull  * NN);    //  4 MB
    float* runoff = (float*)(ws + 8ull  * NN);    //  4 MB
    float* qA     = (float*)(ws + 12ull * NN);    //  4 MB (16 MB total)

    k_pre<<<dim3(NN / 256), dim3(256), 0, stream>>>(bed, pw, status, melt, area,
                                                    phi, inv, runoff);

    dim3 grid(COLS / TILE_W, ROWS / TILE_H), block(NT);   // 32 x 16 = 512 blocks
    k_fused<true,  false><<<grid, block, 0, stream>>>(phi, inv, runoff, runoff, qA, nullptr, nullptr);
    k_fused<false, true ><<<grid, block, 0, stream>>>(phi, inv, runoff, qA, out, cond, status);
}